// Round 1
// baseline (295.382 us; speedup 1.0000x reference)
//
#include <hip/hip_runtime.h>
#include <hip/hip_bf16.h>

#define BSZ 4096
#define DIM 512
#define NCLS 64
#define MARGIN_F 1.0f
#define NT 32                      // 128-tiles per dim
#define NPAIR (NT * (NT + 1) / 2)  // 528 upper-tri pair tiles (by <= bx)
#define NBLK (NPAIR * 2)           // 1056 tiles: 64x128 halves
#define NSL (2 * NT)               // 64-column slices
#define NFIN 16                    // finalize chunks (16*256 = 4096 rows)
#define BK 64                      // k-bytes (=elems) per LDS stage, fp8
#define NKS (DIM / BK)             // 8 stages
#define GRID 1024                  // persistent blocks: exactly 4/CU co-resident

typedef float floatx4 __attribute__((ext_vector_type(4)));
typedef unsigned char u8;

// ---------------- workspace layout ----------------
// [0)        : efp8 BSZ*DIM u8 (2 MiB) normalized fp8-e4m3 embeddings
// [OFF_PP)   : part_ps [NSL][BSZ] float (1 MiB)
// [OFF_PN)   : part_nm [NSL][BSZ] uint  (1 MiB)
// [OFF_ACC)  : f32 total; i32 nv; i32 counter2; i32 norm_done; i32 gemm_done
#define OFF_PP  (BSZ * DIM)
#define OFF_PN  (OFF_PP + NSL * BSZ * 4)
#define OFF_ACC (OFF_PN + NSL * BSZ * 4)

__device__ __forceinline__ void gld_lds16(const u8* g, u8* l) {
    __builtin_amdgcn_global_load_lds(
        (const __attribute__((address_space(1))) unsigned int*)g,
        (__attribute__((address_space(3))) unsigned int*)l, 16, 0, 0);
}

// Single fused persistent kernel: normalize -> spin-barrier -> gemm tiles
// (stride loop over 1056 tiles) -> ticketed barrier -> last-16 blocks finalize.
// Grid = 1024 = 256 CU x 4 blocks (LDS ~26.7K -> 6/CU; launch_bounds caps
// VGPR<=128 -> 4 waves/SIMD), so all blocks co-resident: norm-barrier is
// deadlock-free. The gemm-done barrier spins only in post-work blocks, which
// is deadlock-free regardless of residency.
__global__ __launch_bounds__(256, 4) void ht_fused(
        const float* __restrict__ emb, const int* __restrict__ labels,
        u8* __restrict__ ebf, float* __restrict__ part_ps,
        unsigned* __restrict__ part_nm, float* __restrict__ acc_total,
        int* __restrict__ acc_nv, int* __restrict__ counter2,
        int* __restrict__ norm_done, int* __restrict__ gemm_done,
        float* __restrict__ out) {
    __shared__ u8 sA[2][64 * BK];
    __shared__ u8 sB[2][128 * BK];
    __shared__ int sLI[64];
    __shared__ int sLJ[128];
    __shared__ float sCPps[128];
    __shared__ float sCPnm[128];
    __shared__ int sTicket;
    __shared__ int hist[NCLS];
    __shared__ float sT[4];
    __shared__ int sN[4];

    const int t = threadIdx.x;
    const int lane = t & 63;
    const int wave = t >> 6;

    // ---------- phase 1: L2-normalize + fp8 e4m3 cast (1 row/wave) ----------
    {
        const int row = blockIdx.x * 4 + wave;
        const float4* r4 = (const float4*)(emb + (size_t)row * DIM);
        float4 v0 = r4[lane * 2];
        float4 v1 = r4[lane * 2 + 1];
        float s = v0.x * v0.x + v0.y * v0.y + v0.z * v0.z + v0.w * v0.w
                + v1.x * v1.x + v1.y * v1.y + v1.z * v1.z + v1.w * v1.w;
#pragma unroll
        for (int off = 1; off < 64; off <<= 1) s += __shfl_xor(s, off);
        const float inv = 1.0f / fmaxf(sqrtf(s), 1e-12f);

        int d0 = 0, d1 = 0;
        d0 = __builtin_amdgcn_cvt_pk_fp8_f32(v0.x * inv, v0.y * inv, d0, 0);
        d0 = __builtin_amdgcn_cvt_pk_fp8_f32(v0.z * inv, v0.w * inv, d0, 1);
        d1 = __builtin_amdgcn_cvt_pk_fp8_f32(v1.x * inv, v1.y * inv, d1, 0);
        d1 = __builtin_amdgcn_cvt_pk_fp8_f32(v1.z * inv, v1.w * inv, d1, 1);
        uint2 o; o.x = (unsigned)d0; o.y = (unsigned)d1;
        ((uint2*)(ebf + (size_t)row * DIM))[lane] = o;
    }

    // ---------- grid barrier #1: all ebf rows device-visible ----------
    __threadfence();          // each writer flushes its own stores (agent scope)
    __syncthreads();          // t0's add happens-after all block stores+fences
    if (t == 0) {
        __hip_atomic_fetch_add(norm_done, 1, __ATOMIC_ACQ_REL,
                               __HIP_MEMORY_SCOPE_AGENT);
        while (__hip_atomic_load(norm_done, __ATOMIC_ACQUIRE,
                                 __HIP_MEMORY_SCOPE_AGENT) < GRID)
            __builtin_amdgcn_s_sleep(8);
    }
    __syncthreads();

    // ---------- phase 2: gemm tiles (identical math to proven kernel) ----------
    const int wr = (wave >> 1) * 32;
    const int wc = (wave & 1) * 64;
    const int l15 = lane & 15;
    const int quad = lane >> 4;

    for (int tb = blockIdx.x; tb < NBLK; tb += GRID) {
        __syncthreads();      // protect sLI/sLJ/sCP* vs previous tile's epilogue

        const int p = tb >> 1;
        const int h2 = tb & 1;
        int rem = p, by = 0;
        while (rem >= NT - by) { rem -= NT - by; ++by; }
        const int bx = by + rem;
        const bool offd = (bx != by);

        const int row0 = by * 128 + h2 * 64;
        const int col0 = bx * 128;

        if (t < 64) sLI[t] = labels[row0 + t];
        else if (t < 192) sLJ[t - 64] = labels[col0 + (t - 64)];

        // staging: A 256 segs (1/thread), B 512 segs (2/thread)
        const int sa = t;
        const int ga = (sa & 3) ^ ((sa >> 3) & 3);
        const u8* gA0 = ebf + (size_t)(row0 + (sa >> 2)) * DIM + ga * 16;
        const int sb0 = t, sb1 = 256 + t;
        const int gb0 = (sb0 & 3) ^ ((sb0 >> 3) & 3);
        const int gb1 = (sb1 & 3) ^ ((sb1 >> 3) & 3);
        const u8* gB0 = ebf + (size_t)(col0 + (sb0 >> 2)) * DIM + gb0 * 16;
        const u8* gB1 = ebf + (size_t)(col0 + (sb1 >> 2)) * DIM + gb1 * 16;
        const int lbA = wave * 64 * 16;
        const int lbB0 = wave * 64 * 16;
        const int lbB1 = (256 + wave * 64) * 16;

        floatx4 acc[2][4] = {};

        gld_lds16(gA0, &sA[0][lbA]);
        gld_lds16(gB0, &sB[0][lbB0]);
        gld_lds16(gB1, &sB[0][lbB1]);

        int cur = 0;
        for (int ks = 0; ks < NKS; ++ks) {
            __syncthreads();
            if (ks + 1 < NKS) {
                const int kb = (ks + 1) * BK;
                gld_lds16(gA0 + kb, &sA[cur ^ 1][lbA]);
                gld_lds16(gB0 + kb, &sB[cur ^ 1][lbB0]);
                gld_lds16(gB1 + kb, &sB[cur ^ 1][lbB1]);
            }
#pragma unroll
            for (int h = 0; h < 2; ++h) {
                const int co = (((h * 2 + (quad >> 1)) ^ ((l15 >> 1) & 3)) * 16)
                             + (quad & 1) * 8;
                long af[2]; long bf[4];
#pragma unroll
                for (int mi = 0; mi < 2; ++mi)
                    af[mi] = *(const long*)(&sA[cur][(wr + mi * 16 + l15) * BK + co]);
#pragma unroll
                for (int ni = 0; ni < 4; ++ni)
                    bf[ni] = *(const long*)(&sB[cur][(wc + ni * 16 + l15) * BK + co]);
#pragma unroll
                for (int mi = 0; mi < 2; ++mi)
#pragma unroll
                    for (int ni = 0; ni < 4; ++ni)
                        acc[mi][ni] = __builtin_amdgcn_mfma_f32_16x16x32_fp8_fp8(
                            af[mi], bf[ni], acc[mi][ni], 0, 0, 0);
            }
            cur ^= 1;
        }

        // epilogue: C/D layout col=l15, row=quad*4+reg
        const float INF = __uint_as_float(0x7F800000u);
        const int rslice = 2 * bx + (wc >> 6);
        float psc[4] = {0.f, 0.f, 0.f, 0.f};
        float nmc[4] = {INF, INF, INF, INF};
#pragma unroll
        for (int mi = 0; mi < 2; ++mi) {
            const int rbase = wr + mi * 16 + quad * 4;
#pragma unroll
            for (int r = 0; r < 4; ++r) {
                const int rloc = rbase + r;
                const int gi = row0 + rloc;
                const int rl = sLI[rloc];
                float ps = 0.0f, nm = INF;
#pragma unroll
                for (int ni = 0; ni < 4; ++ni) {
                    const int cloc = wc + ni * 16 + l15;
                    const int gj = col0 + cloc;
                    const int cl = sLJ[cloc];
                    const float d = __builtin_amdgcn_sqrtf(
                        fmaxf(2.0f - 2.0f * acc[mi][ni][r], 0.0f));
                    if (rl == cl) {
                        if (gi != gj) ps += d;
                        if (offd) psc[ni] += d;
                    } else {
                        nm = fminf(nm, d);
                        if (offd) nmc[ni] = fminf(nmc[ni], d);
                    }
                }
#pragma unroll
                for (int off = 1; off < 16; off <<= 1) {
                    ps += __shfl_xor(ps, off);
                    nm = fminf(nm, __shfl_xor(nm, off));
                }
                if (l15 == 0) {
                    part_ps[rslice * BSZ + gi] = ps;
                    part_nm[rslice * BSZ + gi] = __float_as_uint(nm);
                }
            }
        }
        if (offd) {
            const int cslice = 2 * by + h2;
            float cps[4], cnm[4];
#pragma unroll
            for (int ni = 0; ni < 4; ++ni) {
                float ps = psc[ni], nm = nmc[ni];
                ps += __shfl_xor(ps, 16); ps += __shfl_xor(ps, 32);
                nm = fminf(nm, __shfl_xor(nm, 16));
                nm = fminf(nm, __shfl_xor(nm, 32));
                cps[ni] = ps; cnm[ni] = nm;
            }
            if (wave >= 2 && quad == 0) {
#pragma unroll
                for (int ni = 0; ni < 4; ++ni) {
                    const int cl = wc + ni * 16 + l15;
                    sCPps[cl] = cps[ni];
                    sCPnm[cl] = cnm[ni];
                }
            }
            __syncthreads();
            if (wave < 2 && quad == 0) {
#pragma unroll
                for (int ni = 0; ni < 4; ++ni) {
                    const int cl = wc + ni * 16 + l15;
                    const int gj = col0 + cl;
                    const float ps = cps[ni] + sCPps[cl];
                    const float nm = fminf(cnm[ni], sCPnm[cl]);
                    part_ps[cslice * BSZ + gj] = ps;
                    part_nm[cslice * BSZ + gj] = __float_as_uint(nm);
                }
            }
        }
    }

    // ---------- grid barrier #2 (ticketed): last 16 blocks finalize ----------
    __threadfence();
    __syncthreads();
    if (t == 0)
        sTicket = __hip_atomic_fetch_add(gemm_done, 1, __ATOMIC_ACQ_REL,
                                         __HIP_MEMORY_SCOPE_AGENT);
    __syncthreads();
    const int ticket = sTicket;
    if (ticket < GRID - NFIN) return;    // uniform per-block exit
    if (t == 0) {
        while (__hip_atomic_load(gemm_done, __ATOMIC_ACQUIRE,
                                 __HIP_MEMORY_SCOPE_AGENT) < GRID)
            __builtin_amdgcn_s_sleep(8);
    }
    __syncthreads();

    // ---------- phase 3: finalize one 256-row chunk ----------
    const int chunk = ticket - (GRID - NFIN);
    if (t < NCLS) hist[t] = 0;
    __syncthreads();
    for (int i = t; i < BSZ; i += 256) atomicAdd(&hist[labels[i]], 1);
    __syncthreads();

    const int j = chunk * 256 + t;
    float ps = 0.0f;
    float nm = __uint_as_float(0x7F800000u);
#pragma unroll 8
    for (int s = 0; s < NSL; ++s) {
        ps += part_ps[s * BSZ + j];
        nm = fminf(nm, __uint_as_float(part_nm[s * BSZ + j]));
    }
    const int cnt = hist[labels[j]];
    const int pc = cnt - 1;
    const int nc = BSZ - cnt;
    float loss = 0.0f;
    int lv = 0;
    if (pc > 0 && nc > 0) {
        loss = fmaxf(ps / (float)pc - nm + MARGIN_F, 0.0f);
        lv = 1;
    }
#pragma unroll
    for (int off = 1; off < 64; off <<= 1) {
        loss += __shfl_xor(loss, off);
        lv += __shfl_xor(lv, off);
    }
    if ((t & 63) == 0) { sT[t >> 6] = loss; sN[t >> 6] = lv; }
    __syncthreads();
    if (t == 0) {
        const float tt = sT[0] + sT[1] + sT[2] + sT[3];
        const int nn = sN[0] + sN[1] + sN[2] + sN[3];
        __hip_atomic_fetch_add(acc_total, tt, __ATOMIC_ACQ_REL,
                               __HIP_MEMORY_SCOPE_AGENT);
        __hip_atomic_fetch_add(acc_nv, nn, __ATOMIC_ACQ_REL,
                               __HIP_MEMORY_SCOPE_AGENT);
        const int old2 = __hip_atomic_fetch_add(counter2, 1, __ATOMIC_ACQ_REL,
                                                __HIP_MEMORY_SCOPE_AGENT);
        if (old2 == NFIN - 1) {
            const float ft = __hip_atomic_load(acc_total, __ATOMIC_ACQUIRE,
                                               __HIP_MEMORY_SCOPE_AGENT);
            const int fn = __hip_atomic_load(acc_nv, __ATOMIC_ACQUIRE,
                                             __HIP_MEMORY_SCOPE_AGENT);
            out[0] = (fn > 0) ? ft / (float)fn : 0.0f;
        }
    }
}

extern "C" void kernel_launch(void* const* d_in, const int* in_sizes, int n_in,
                              void* d_out, int out_size, void* d_ws, size_t ws_size,
                              hipStream_t stream) {
    const float* emb = (const float*)d_in[0];
    const int* labels = (const int*)d_in[1];
    float* out = (float*)d_out;
    char* ws = (char*)d_ws;

    u8* ebf = (u8*)ws;
    float* part_ps = (float*)(ws + OFF_PP);
    unsigned* part_nm = (unsigned*)(ws + OFF_PN);
    float* acc_total = (float*)(ws + OFF_ACC);
    int* acc_nv = (int*)(ws + OFF_ACC + 4);
    int* counter2 = (int*)(ws + OFF_ACC + 8);
    int* norm_done = (int*)(ws + OFF_ACC + 12);
    int* gemm_done = (int*)(ws + OFF_ACC + 16);

    // barrier/accumulator init under poisoned workspace (graph-capturable node)
    hipMemsetAsync(ws + OFF_ACC, 0, 32, stream);
    ht_fused<<<GRID, 256, 0, stream>>>(emb, labels, ebf, part_ps, part_nm,
                                       acc_total, acc_nv, counter2,
                                       norm_done, gemm_done, out);
}

// Round 2
// 88.714 us; speedup vs baseline: 3.3296x; 3.3296x over previous
//
#include <hip/hip_runtime.h>
#include <hip/hip_bf16.h>

#define BSZ 4096
#define DIM 512
#define NCLS 64
#define MARGIN_F 1.0f
#define NT 32                      // 128-tiles per dim
#define NPAIR (NT * (NT + 1) / 2)  // 528 upper-tri pair tiles (by <= bx)
#define NSL (2 * NT)               // 64-column slices
#define NFIN 16                    // finalize blocks (16*256 = 4096 rows)
#define BK 64                      // k-bytes (=elems) per LDS stage, fp8
#define NKS (DIM / BK)             // 8 stages

typedef float floatx4 __attribute__((ext_vector_type(4)));
typedef unsigned char u8;

// ---------------- workspace layout ----------------
// [0)        : efp8 BSZ*DIM u8 (2 MiB) normalized fp8-e4m3 embeddings
// [OFF_PP)   : part_ps [NSL][BSZ] float (1 MiB) row j vs 64-col group s
// [OFF_PN)   : part_nm [NSL][BSZ] uint  (1 MiB) (float bits; dist>=0)
// [OFF_ACC)  : float total; int nv; int counter2
#define OFF_PP  (BSZ * DIM)
#define OFF_PN  (OFF_PP + NSL * BSZ * 4)
#define OFF_ACC (OFF_PN + NSL * BSZ * 4)

// async global->LDS, 16 B/lane; LDS dest = wave-uniform base + lane*16
__device__ __forceinline__ void gld_lds16(const u8* g, u8* l) {
    __builtin_amdgcn_global_load_lds(
        (const __attribute__((address_space(1))) unsigned int*)g,
        (__attribute__((address_space(3))) unsigned int*)l, 16, 0, 0);
}

// 4 waves/block, one row/wave: L2-normalize, cast fp8 e4m3 (OCP, HW cvt);
// init scalar accums.
__global__ __launch_bounds__(256) void ht_normalize(
        const float* __restrict__ emb, u8* __restrict__ ebf,
        float* __restrict__ acc_total, int* __restrict__ acc_nv,
        int* __restrict__ counter2) {
    const int lane = threadIdx.x & 63;
    const int row = blockIdx.x * 4 + (threadIdx.x >> 6);
    const float4* r4 = (const float4*)(emb + (size_t)row * DIM);
    float4 v0 = r4[lane * 2];
    float4 v1 = r4[lane * 2 + 1];
    float s = v0.x * v0.x + v0.y * v0.y + v0.z * v0.z + v0.w * v0.w
            + v1.x * v1.x + v1.y * v1.y + v1.z * v1.z + v1.w * v1.w;
#pragma unroll
    for (int off = 1; off < 64; off <<= 1) s += __shfl_xor(s, off);
    const float inv = 1.0f / fmaxf(sqrtf(s), 1e-12f);

    int d0 = 0, d1 = 0;
    d0 = __builtin_amdgcn_cvt_pk_fp8_f32(v0.x * inv, v0.y * inv, d0, 0);
    d0 = __builtin_amdgcn_cvt_pk_fp8_f32(v0.z * inv, v0.w * inv, d0, 1);
    d1 = __builtin_amdgcn_cvt_pk_fp8_f32(v1.x * inv, v1.y * inv, d1, 0);
    d1 = __builtin_amdgcn_cvt_pk_fp8_f32(v1.z * inv, v1.w * inv, d1, 1);
    uint2 o; o.x = (unsigned)d0; o.y = (unsigned)d1;
    ((uint2*)(ebf + (size_t)row * DIM))[lane] = o;   // bytes lane*8..+7

    if (blockIdx.x == 0 && threadIdx.x == 0) {
        *acc_total = 0.0f; *acc_nv = 0; *counter2 = 0;
    }
}

// One block per upper-tri pair (by <= bx): full 128x128 fp8 tile.
// 4 waves in 2x2: wr=(wave>>1)*64, wc=(wave&1)*64, each wave owns a 64x64
// quadrant (acc[4][4] 16x16 tiles). vs the 64x128-half version this fetches
// and ds_reads each A panel ONCE (-33% staging segs, -33% ds_reads, half the
// barriers) and 528 blocks <= 1024 co-resident slots -> single dispatch round.
// LDS 33.8 KB -> 4 blocks/CU; launch_bounds(256,4) caps VGPR at 128.
// Staging: seg s (16B): row=s>>2, LDS container s&3, global container
// (s&3)^((s>>3)&3) (xor-swizzle inside each row's 64B -> coalescing kept).
// Fragment (mfma_f32_16x16x32_fp8_fp8, k=quad*8+j, 2 halves h per stage):
// ds_read_b64 at container (h*2+(quad>>1))^((l15>>1)&3), half quad&1 ->
// conflict-free floor (same pattern as verified 64x128 version).
// Epilogue partials: exactly one writer per part[s][j] -> plain stores.
// Col stats: wave (wr>>6, wc>>6) solely owns cslice=2*by+(wr>>6) cols
// wc..wc+63 -> no cross-wave combine needed.
__global__ __launch_bounds__(256, 4) void ht_gemm_reduce(
        const u8* __restrict__ ebf, const int* __restrict__ labels,
        float* __restrict__ part_ps, unsigned* __restrict__ part_nm) {
    __shared__ u8 sA[2][128 * BK];
    __shared__ u8 sB[2][128 * BK];
    __shared__ int sLI[128];
    __shared__ int sLJ[128];

    const int p = blockIdx.x;            // upper-tri pair index
    int rem = p, by = 0;
    while (rem >= NT - by) { rem -= NT - by; ++by; }
    const int bx = by + rem;
    const bool offd = (bx != by);

    const int t = threadIdx.x;
    const int row0 = by * 128;
    const int col0 = bx * 128;

    if (t < 128) sLI[t] = labels[row0 + t];
    else sLJ[t - 128] = labels[col0 + (t - 128)];

    const int lane = t & 63;
    const int wave = t >> 6;
    const int wr = (wave >> 1) * 64;
    const int wc = (wave & 1) * 64;
    const int l15 = lane & 15;
    const int quad = lane >> 4;

    // staging: A 512 segs (2/thread), B 512 segs (2/thread)
    // seg t -> row t>>2; seg 256+t -> row 64+(t>>2); container swizzle is
    // identical for both (256 is 8-aligned in seg index): gc=(t&3)^((t>>3)&3)
    const int gc = (t & 3) ^ ((t >> 3) & 3);
    const u8* gA0 = ebf + (size_t)(row0 + (t >> 2)) * DIM + gc * 16;
    const u8* gA1 = ebf + (size_t)(row0 + 64 + (t >> 2)) * DIM + gc * 16;
    const u8* gB0 = ebf + (size_t)(col0 + (t >> 2)) * DIM + gc * 16;
    const u8* gB1 = ebf + (size_t)(col0 + 64 + (t >> 2)) * DIM + gc * 16;
    const int lb0 = wave * 64 * 16;          // wave-uniform LDS byte bases
    const int lb1 = (256 + wave * 64) * 16;

    floatx4 acc[4][4] = {};

    gld_lds16(gA0, &sA[0][lb0]);
    gld_lds16(gA1, &sA[0][lb1]);
    gld_lds16(gB0, &sB[0][lb0]);
    gld_lds16(gB1, &sB[0][lb1]);

    int cur = 0;
    for (int ks = 0; ks < NKS; ++ks) {
        __syncthreads();  // vmcnt drained: buf[cur] ready; buf[cur^1] reads done
        if (ks + 1 < NKS) {
            const int kb = (ks + 1) * BK;
            gld_lds16(gA0 + kb, &sA[cur ^ 1][lb0]);
            gld_lds16(gA1 + kb, &sA[cur ^ 1][lb1]);
            gld_lds16(gB0 + kb, &sB[cur ^ 1][lb0]);
            gld_lds16(gB1 + kb, &sB[cur ^ 1][lb1]);
        }
#pragma unroll
        for (int h = 0; h < 2; ++h) {
            // swizzled container + 8B half within it
            const int co = (((h * 2 + (quad >> 1)) ^ ((l15 >> 1) & 3)) * 16)
                         + (quad & 1) * 8;
            long af[4]; long bf[4];
#pragma unroll
            for (int mi = 0; mi < 4; ++mi)
                af[mi] = *(const long*)(&sA[cur][(wr + mi * 16 + l15) * BK + co]);
#pragma unroll
            for (int ni = 0; ni < 4; ++ni)
                bf[ni] = *(const long*)(&sB[cur][(wc + ni * 16 + l15) * BK + co]);
#pragma unroll
            for (int mi = 0; mi < 4; ++mi)
#pragma unroll
                for (int ni = 0; ni < 4; ++ni)
                    acc[mi][ni] = __builtin_amdgcn_mfma_f32_16x16x32_fp8_fp8(
                        af[mi], bf[ni], acc[mi][ni], 0, 0, 0);
        }
        cur ^= 1;
    }

    // epilogue: C/D layout col=l15, row=quad*4+reg (shape-determined)
    const float INF = __uint_as_float(0x7F800000u);
    const int rslice = 2 * bx + (wc >> 6);
    float psc[4] = {0.f, 0.f, 0.f, 0.f};
    float nmc[4] = {INF, INF, INF, INF};
#pragma unroll
    for (int mi = 0; mi < 4; ++mi) {
        const int rbase = wr + mi * 16 + quad * 4;
#pragma unroll
        for (int r = 0; r < 4; ++r) {
            const int rloc = rbase + r;
            const int gi = row0 + rloc;
            const int rl = sLI[rloc];
            float ps = 0.0f, nm = INF;
#pragma unroll
            for (int ni = 0; ni < 4; ++ni) {
                const int cloc = wc + ni * 16 + l15;
                const int gj = col0 + cloc;
                const int cl = sLJ[cloc];
                const float d = __builtin_amdgcn_sqrtf(
                    fmaxf(2.0f - 2.0f * acc[mi][ni][r], 0.0f));
                if (rl == cl) {
                    if (gi != gj) ps += d;      // drop self-pair (diag only)
                    if (offd) psc[ni] += d;
                } else {
                    nm = fminf(nm, d);
                    if (offd) nmc[ni] = fminf(nmc[ni], d);
                }
            }
#pragma unroll
            for (int off = 1; off < 16; off <<= 1) {
                ps += __shfl_xor(ps, off);
                nm = fminf(nm, __shfl_xor(nm, off));
            }
            if (l15 == 0) {                 // sole writer of (rslice, gi)
                part_ps[rslice * BSZ + gi] = ps;
                part_nm[rslice * BSZ + gi] = __float_as_uint(nm);
            }
        }
    }
    if (offd) {
        // col stats: this wave solely owns cslice=2*by+(wr>>6), cols wc..wc+63
        // (64 rows summed: 16 per lane over mi,r + quad tree via xor16/xor32)
        const int cslice = 2 * by + (wr >> 6);
#pragma unroll
        for (int ni = 0; ni < 4; ++ni) {
            float ps = psc[ni], nm = nmc[ni];
            ps += __shfl_xor(ps, 16); ps += __shfl_xor(ps, 32);
            nm = fminf(nm, __shfl_xor(nm, 16));
            nm = fminf(nm, __shfl_xor(nm, 32));
            if (quad == 0) {
                const int gj = col0 + wc + ni * 16 + l15;
                part_ps[cslice * BSZ + gj] = ps;
                part_nm[cslice * BSZ + gj] = __float_as_uint(nm);
            }
        }
    }
}

// 16 blocks x 256 threads: one row per thread. Reduce 64 slices (coalesced),
// per-block loss partials -> 2 device atomics per block; last block writes out.
__global__ __launch_bounds__(256) void ht_finalize(
        const float* __restrict__ part_ps, const unsigned* __restrict__ part_nm,
        const int* __restrict__ labels, float* __restrict__ acc_total,
        int* __restrict__ acc_nv, int* __restrict__ counter2,
        float* __restrict__ out) {
    __shared__ int hist[NCLS];
    __shared__ float sT[4];
    __shared__ int sN[4];
    const int t = threadIdx.x;
    if (t < NCLS) hist[t] = 0;
    __syncthreads();
    for (int i = t; i < BSZ; i += 256) atomicAdd(&hist[labels[i]], 1);
    __syncthreads();

    const int j = blockIdx.x * 256 + t;
    float ps = 0.0f;
    float nm = __uint_as_float(0x7F800000u);
#pragma unroll 8
    for (int s = 0; s < NSL; ++s) {
        ps += part_ps[s * BSZ + j];
        nm = fminf(nm, __uint_as_float(part_nm[s * BSZ + j]));
    }
    const int cnt = hist[labels[j]];
    const int pc = cnt - 1;
    const int nc = BSZ - cnt;
    float loss = 0.0f;
    int lv = 0;
    if (pc > 0 && nc > 0) {
        loss = fmaxf(ps / (float)pc - nm + MARGIN_F, 0.0f);
        lv = 1;
    }
#pragma unroll
    for (int off = 1; off < 64; off <<= 1) {
        loss += __shfl_xor(loss, off);
        lv += __shfl_xor(lv, off);
    }
    if ((t & 63) == 0) { sT[t >> 6] = loss; sN[t >> 6] = lv; }
    __syncthreads();
    if (t == 0) {
        const float tt = sT[0] + sT[1] + sT[2] + sT[3];
        const int nn = sN[0] + sN[1] + sN[2] + sN[3];
        __hip_atomic_fetch_add(acc_total, tt, __ATOMIC_ACQ_REL,
                               __HIP_MEMORY_SCOPE_AGENT);
        __hip_atomic_fetch_add(acc_nv, nn, __ATOMIC_ACQ_REL,
                               __HIP_MEMORY_SCOPE_AGENT);
        const int old2 = __hip_atomic_fetch_add(counter2, 1, __ATOMIC_ACQ_REL,
                                                __HIP_MEMORY_SCOPE_AGENT);
        if (old2 == NFIN - 1) {
            const float ft = __hip_atomic_load(acc_total, __ATOMIC_ACQUIRE,
                                               __HIP_MEMORY_SCOPE_AGENT);
            const int fn = __hip_atomic_load(acc_nv, __ATOMIC_ACQUIRE,
                                             __HIP_MEMORY_SCOPE_AGENT);
            out[0] = (fn > 0) ? ft / (float)fn : 0.0f;
        }
    }
}

extern "C" void kernel_launch(void* const* d_in, const int* in_sizes, int n_in,
                              void* d_out, int out_size, void* d_ws, size_t ws_size,
                              hipStream_t stream) {
    const float* emb = (const float*)d_in[0];
    const int* labels = (const int*)d_in[1];
    float* out = (float*)d_out;
    char* ws = (char*)d_ws;

    u8* ebf = (u8*)ws;
    float* part_ps = (float*)(ws + OFF_PP);
    unsigned* part_nm = (unsigned*)(ws + OFF_PN);
    float* acc_total = (float*)(ws + OFF_ACC);
    int* acc_nv = (int*)(ws + OFF_ACC + 4);
    int* counter2 = (int*)(ws + OFF_ACC + 8);

    ht_normalize<<<BSZ / 4, 256, 0, stream>>>(emb, labels ? ebf : ebf, acc_total,
                                              acc_nv, counter2);
    ht_gemm_reduce<<<NPAIR, 256, 0, stream>>>(ebf, labels, part_ps, part_nm);
    ht_finalize<<<NFIN, 256, 0, stream>>>(part_ps, part_nm, labels,
                                          acc_total, acc_nv, counter2, out);
}

// Round 3
// 86.963 us; speedup vs baseline: 3.3967x; 1.0201x over previous
//
#include <hip/hip_runtime.h>
#include <hip/hip_bf16.h>

#define BSZ 4096
#define DIM 512
#define NCLS 64
#define MARGIN_F 1.0f
#define NT 32                      // 128-tiles per dim
#define NPAIR (NT * (NT + 1) / 2)  // 528 upper-tri pair tiles (by <= bx)
#define NSL (2 * NT)               // 64-column slices
#define NFIN 16                    // finalize blocks (16*256 = 4096 rows)
#define BK 64                      // k-bytes (=elems) per LDS stage, fp8
#define NKS (DIM / BK)             // 8 stages

typedef float floatx4 __attribute__((ext_vector_type(4)));
typedef unsigned char u8;

// ---------------- workspace layout ----------------
// [0)        : efp8 BSZ*DIM u8 (2 MiB) normalized fp8-e4m3 embeddings
// [OFF_PP)   : part_ps [NSL][BSZ] float (1 MiB) row j vs 64-col group s
// [OFF_PN)   : part_nm [NSL][BSZ] uint  (1 MiB) (float bits; dist>=0)
// [OFF_ACC)  : float total; int nv; int counter2
#define OFF_PP  (BSZ * DIM)
#define OFF_PN  (OFF_PP + NSL * BSZ * 4)
#define OFF_ACC (OFF_PN + NSL * BSZ * 4)

// async global->LDS, 16 B/lane; LDS dest = wave-uniform base + lane*16
__device__ __forceinline__ void gld_lds16(const u8* g, u8* l) {
    __builtin_amdgcn_global_load_lds(
        (const __attribute__((address_space(1))) unsigned int*)g,
        (__attribute__((address_space(3))) unsigned int*)l, 16, 0, 0);
}

// 4 waves/block, one row/wave: L2-normalize, cast fp8 e4m3 (OCP, HW cvt);
// init scalar accums.
__global__ __launch_bounds__(256) void ht_normalize(
        const float* __restrict__ emb, u8* __restrict__ ebf,
        float* __restrict__ acc_total, int* __restrict__ acc_nv,
        int* __restrict__ counter2) {
    const int lane = threadIdx.x & 63;
    const int row = blockIdx.x * 4 + (threadIdx.x >> 6);
    const float4* r4 = (const float4*)(emb + (size_t)row * DIM);
    float4 v0 = r4[lane * 2];
    float4 v1 = r4[lane * 2 + 1];
    float s = v0.x * v0.x + v0.y * v0.y + v0.z * v0.z + v0.w * v0.w
            + v1.x * v1.x + v1.y * v1.y + v1.z * v1.z + v1.w * v1.w;
#pragma unroll
    for (int off = 1; off < 64; off <<= 1) s += __shfl_xor(s, off);
    const float inv = 1.0f / fmaxf(sqrtf(s), 1e-12f);

    int d0 = 0, d1 = 0;
    d0 = __builtin_amdgcn_cvt_pk_fp8_f32(v0.x * inv, v0.y * inv, d0, 0);
    d0 = __builtin_amdgcn_cvt_pk_fp8_f32(v0.z * inv, v0.w * inv, d0, 1);
    d1 = __builtin_amdgcn_cvt_pk_fp8_f32(v1.x * inv, v1.y * inv, d1, 0);
    d1 = __builtin_amdgcn_cvt_pk_fp8_f32(v1.z * inv, v1.w * inv, d1, 1);
    uint2 o; o.x = (unsigned)d0; o.y = (unsigned)d1;
    ((uint2*)(ebf + (size_t)row * DIM))[lane] = o;   // bytes lane*8..+7

    if (blockIdx.x == 0 && threadIdx.x == 0) {
        *acc_total = 0.0f; *acc_nv = 0; *counter2 = 0;
    }
}

// One block per upper-tri pair (by <= bx): full 128x128 fp8 tile, 4 waves in
// 2x2 (wave owns a 64x64 quadrant, acc[4][4]).
// Round-3 change vs verified R2: TRIPLE-buffered LDS + counted vmcnt at a raw
// s_barrier (prefetch distance 2). Each wave waits only its OWN stage-k loads
// (vmcnt(4): newest 4 in flight = stage k+1) instead of the compiler's full
// vmcnt(0)+lgkmcnt(0) drain -> per-stage drain stall ~0 (loads get ~2 compute
// stages to land vs ~200-400cy L2 latency). LDS 49.3 KB -> 3 blocks/CU =
// 12 waves/CU (was 2/CU = 8), and 528 <= 768 slots -> single residency round.
// Race audit: stage k+2 LDS-writes issue only after barrier k, which orders
// them after ALL waves' iter-(k-1) reads of that buffer; per-wave vmcnt is
// FIFO so vmcnt(4) guarantees stage-k complete; iter-0 wait adds lgkmcnt(0)
// for label ds_write visibility; sched_barrier(0) fences compiler motion
// across the raw barrier (rule #18). All arithmetic identical to R2.
__global__ __launch_bounds__(256, 4) void ht_gemm_reduce(
        const u8* __restrict__ ebf, const int* __restrict__ labels,
        float* __restrict__ part_ps, unsigned* __restrict__ part_nm) {
    __shared__ u8 sA[3][128 * BK];
    __shared__ u8 sB[3][128 * BK];
    __shared__ int sLI[128];
    __shared__ int sLJ[128];

    const int p = blockIdx.x;            // upper-tri pair index
    int rem = p, by = 0;
    while (rem >= NT - by) { rem -= NT - by; ++by; }
    const int bx = by + rem;
    const bool offd = (bx != by);

    const int t = threadIdx.x;
    const int row0 = by * 128;
    const int col0 = bx * 128;

    if (t < 128) sLI[t] = labels[row0 + t];
    else sLJ[t - 128] = labels[col0 + (t - 128)];

    const int lane = t & 63;
    const int wave = t >> 6;
    const int wr = (wave >> 1) * 64;
    const int wc = (wave & 1) * 64;
    const int l15 = lane & 15;
    const int quad = lane >> 4;

    // staging: A 512 segs (2/thread), B 512 segs (2/thread)
    // seg s (16B): row=s>>2, LDS container s&3, global container
    // (s&3)^((s>>3)&3) (xor-swizzle inside each row's 64B, coalescing kept)
    const int gc = (t & 3) ^ ((t >> 3) & 3);
    const u8* gA0 = ebf + (size_t)(row0 + (t >> 2)) * DIM + gc * 16;
    const u8* gA1 = ebf + (size_t)(row0 + 64 + (t >> 2)) * DIM + gc * 16;
    const u8* gB0 = ebf + (size_t)(col0 + (t >> 2)) * DIM + gc * 16;
    const u8* gB1 = ebf + (size_t)(col0 + 64 + (t >> 2)) * DIM + gc * 16;
    const int lb0 = wave * 64 * 16;          // wave-uniform LDS byte bases
    const int lb1 = (256 + wave * 64) * 16;

    floatx4 acc[4][4] = {};

    // prologue: stages 0 and 1 in flight (8 loads/wave outstanding)
    gld_lds16(gA0, &sA[0][lb0]);
    gld_lds16(gA1, &sA[0][lb1]);
    gld_lds16(gB0, &sB[0][lb0]);
    gld_lds16(gB1, &sB[0][lb1]);
    gld_lds16(gA0 + BK, &sA[1][lb0]);
    gld_lds16(gA1 + BK, &sA[1][lb1]);
    gld_lds16(gB0 + BK, &sB[1][lb0]);
    gld_lds16(gB1 + BK, &sB[1][lb1]);

#pragma unroll
    for (int ks = 0; ks < NKS; ++ks) {
        // own stage-k loads landed (newest 4 = stage k+1 may stay in flight)
        if (ks == 0)
            asm volatile("s_waitcnt vmcnt(4) lgkmcnt(0)" ::: "memory");
        else if (ks < NKS - 1)
            asm volatile("s_waitcnt vmcnt(4)" ::: "memory");
        else
            asm volatile("s_waitcnt vmcnt(0)" ::: "memory");
        __builtin_amdgcn_s_barrier();      // everyone's stage-k in LDS;
                                           // everyone done reading buf[(k+2)%3]
        __builtin_amdgcn_sched_barrier(0);

        if (ks + 2 < NKS) {
            const int kb = (ks + 2) * BK;
            const int bn = (ks + 2) % 3;   // constant after unroll
            gld_lds16(gA0 + kb, &sA[bn][lb0]);
            gld_lds16(gA1 + kb, &sA[bn][lb1]);
            gld_lds16(gB0 + kb, &sB[bn][lb0]);
            gld_lds16(gB1 + kb, &sB[bn][lb1]);
        }
        const int bc = ks % 3;             // constant after unroll
#pragma unroll
        for (int h = 0; h < 2; ++h) {
            // swizzled container + 8B half within it (conflict-free floor)
            const int co = (((h * 2 + (quad >> 1)) ^ ((l15 >> 1) & 3)) * 16)
                         + (quad & 1) * 8;
            long af[4]; long bf[4];
#pragma unroll
            for (int mi = 0; mi < 4; ++mi)
                af[mi] = *(const long*)(&sA[bc][(wr + mi * 16 + l15) * BK + co]);
#pragma unroll
            for (int ni = 0; ni < 4; ++ni)
                bf[ni] = *(const long*)(&sB[bc][(wc + ni * 16 + l15) * BK + co]);
#pragma unroll
            for (int mi = 0; mi < 4; ++mi)
#pragma unroll
                for (int ni = 0; ni < 4; ++ni)
                    acc[mi][ni] = __builtin_amdgcn_mfma_f32_16x16x32_fp8_fp8(
                        af[mi], bf[ni], acc[mi][ni], 0, 0, 0);
        }
    }

    // epilogue: C/D layout col=l15, row=quad*4+reg (shape-determined)
    const float INF = __uint_as_float(0x7F800000u);
    const int rslice = 2 * bx + (wc >> 6);
    float psc[4] = {0.f, 0.f, 0.f, 0.f};
    float nmc[4] = {INF, INF, INF, INF};
#pragma unroll
    for (int mi = 0; mi < 4; ++mi) {
        const int rbase = wr + mi * 16 + quad * 4;
#pragma unroll
        for (int r = 0; r < 4; ++r) {
            const int rloc = rbase + r;
            const int gi = row0 + rloc;
            const int rl = sLI[rloc];
            float ps = 0.0f, nm = INF;
#pragma unroll
            for (int ni = 0; ni < 4; ++ni) {
                const int cloc = wc + ni * 16 + l15;
                const int gj = col0 + cloc;
                const int cl = sLJ[cloc];
                const float d = __builtin_amdgcn_sqrtf(
                    fmaxf(2.0f - 2.0f * acc[mi][ni][r], 0.0f));
                if (rl == cl) {
                    if (gi != gj) ps += d;      // drop self-pair (diag only)
                    if (offd) psc[ni] += d;
                } else {
                    nm = fminf(nm, d);
                    if (offd) nmc[ni] = fminf(nmc[ni], d);
                }
            }
#pragma unroll
            for (int off = 1; off < 16; off <<= 1) {
                ps += __shfl_xor(ps, off);
                nm = fminf(nm, __shfl_xor(nm, off));
            }
            if (l15 == 0) {                 // sole writer of (rslice, gi)
                part_ps[rslice * BSZ + gi] = ps;
                part_nm[rslice * BSZ + gi] = __float_as_uint(nm);
            }
        }
    }
    if (offd) {
        // col stats: this wave solely owns cslice=2*by+(wr>>6), cols wc..wc+63
        const int cslice = 2 * by + (wr >> 6);
#pragma unroll
        for (int ni = 0; ni < 4; ++ni) {
            float ps = psc[ni], nm = nmc[ni];
            ps += __shfl_xor(ps, 16); ps += __shfl_xor(ps, 32);
            nm = fminf(nm, __shfl_xor(nm, 16));
            nm = fminf(nm, __shfl_xor(nm, 32));
            if (quad == 0) {
                const int gj = col0 + wc + ni * 16 + l15;
                part_ps[cslice * BSZ + gj] = ps;
                part_nm[cslice * BSZ + gj] = __float_as_uint(nm);
            }
        }
    }
}

// 16 blocks x 256 threads: one row per thread. Reduce 64 slices (coalesced),
// per-block loss partials -> 2 device atomics per block; last block writes out.
__global__ __launch_bounds__(256) void ht_finalize(
        const float* __restrict__ part_ps, const unsigned* __restrict__ part_nm,
        const int* __restrict__ labels, float* __restrict__ acc_total,
        int* __restrict__ acc_nv, int* __restrict__ counter2,
        float* __restrict__ out) {
    __shared__ int hist[NCLS];
    __shared__ float sT[4];
    __shared__ int sN[4];
    const int t = threadIdx.x;
    if (t < NCLS) hist[t] = 0;
    __syncthreads();
    for (int i = t; i < BSZ; i += 256) atomicAdd(&hist[labels[i]], 1);
    __syncthreads();

    const int j = blockIdx.x * 256 + t;
    float ps = 0.0f;
    float nm = __uint_as_float(0x7F800000u);
#pragma unroll 8
    for (int s = 0; s < NSL; ++s) {
        ps += part_ps[s * BSZ + j];
        nm = fminf(nm, __uint_as_float(part_nm[s * BSZ + j]));
    }
    const int cnt = hist[labels[j]];
    const int pc = cnt - 1;
    const int nc = BSZ - cnt;
    float loss = 0.0f;
    int lv = 0;
    if (pc > 0 && nc > 0) {
        loss = fmaxf(ps / (float)pc - nm + MARGIN_F, 0.0f);
        lv = 1;
    }
#pragma unroll
    for (int off = 1; off < 64; off <<= 1) {
        loss += __shfl_xor(loss, off);
        lv += __shfl_xor(lv, off);
    }
    if ((t & 63) == 0) { sT[t >> 6] = loss; sN[t >> 6] = lv; }
    __syncthreads();
    if (t == 0) {
        const float tt = sT[0] + sT[1] + sT[2] + sT[3];
        const int nn = sN[0] + sN[1] + sN[2] + sN[3];
        __hip_atomic_fetch_add(acc_total, tt, __ATOMIC_ACQ_REL,
                               __HIP_MEMORY_SCOPE_AGENT);
        __hip_atomic_fetch_add(acc_nv, nn, __ATOMIC_ACQ_REL,
                               __HIP_MEMORY_SCOPE_AGENT);
        const int old2 = __hip_atomic_fetch_add(counter2, 1, __ATOMIC_ACQ_REL,
                                                __HIP_MEMORY_SCOPE_AGENT);
        if (old2 == NFIN - 1) {
            const float ft = __hip_atomic_load(acc_total, __ATOMIC_ACQUIRE,
                                               __HIP_MEMORY_SCOPE_AGENT);
            const int fn = __hip_atomic_load(acc_nv, __ATOMIC_ACQUIRE,
                                             __HIP_MEMORY_SCOPE_AGENT);
            out[0] = (fn > 0) ? ft / (float)fn : 0.0f;
        }
    }
}

extern "C" void kernel_launch(void* const* d_in, const int* in_sizes, int n_in,
                              void* d_out, int out_size, void* d_ws, size_t ws_size,
                              hipStream_t stream) {
    const float* emb = (const float*)d_in[0];
    const int* labels = (const int*)d_in[1];
    float* out = (float*)d_out;
    char* ws = (char*)d_ws;

    u8* ebf = (u8*)ws;
    float* part_ps = (float*)(ws + OFF_PP);
    unsigned* part_nm = (unsigned*)(ws + OFF_PN);
    float* acc_total = (float*)(ws + OFF_ACC);
    int* acc_nv = (int*)(ws + OFF_ACC + 4);
    int* counter2 = (int*)(ws + OFF_ACC + 8);

    ht_normalize<<<BSZ / 4, 256, 0, stream>>>(emb, ebf, acc_total, acc_nv,
                                              counter2);
    ht_gemm_reduce<<<NPAIR, 256, 0, stream>>>(ebf, labels, part_ps, part_nm);
    ht_finalize<<<NFIN, 256, 0, stream>>>(part_ps, part_nm, labels,
                                          acc_total, acc_nv, counter2, out);
}